// Round 5
// baseline (132.040 us; speedup 1.0000x reference)
//
#include <hip/hip_runtime.h>
#include <hip/hip_bf16.h>

// ---------- types ----------
typedef __attribute__((ext_vector_type(8))) short short8;
typedef __attribute__((ext_vector_type(4))) float f32x4;

__device__ __forceinline__ short tobf(float f) {
  __hip_bfloat16 h = __float2bfloat16(f);
  return *reinterpret_cast<short*>(&h);
}

// XOR swizzle of the 16B-column index within a 128B LDS row (G4 / T2).
__device__ __forceinline__ int swz(int row) { return (row ^ (row >> 3)) & 7; }

#define GLDS16(gp, lp) __builtin_amdgcn_global_load_lds( \
    (__attribute__((address_space(1))) void*)(gp),       \
    (__attribute__((address_space(3))) void*)(lp), 16, 0, 0)

// q pre-scale folded into QKV-GEMM epilogue: S = (q*alpha)·k is then in
// log2 domain with the 1/sqrt(64) attention scale included -> attn uses exp2.
#define QSCALE 0.18033688011112042f  // 0.125 * log2(e)

// ---------- fused prep kernel ----------
// blocks 0..1023    : x f32 -> bf16 (4096x1024)
// blocks 1024..1407 : transpose Wqkv [1024][1536] -> [1536][1024] bf16
// blocks 1408..1663 : transpose Wout [1024][1024] -> [1024][1024] bf16
// blocks 1664..1919 : RoPE tables [2048][32] cos/sin
__global__ __launch_bounds__(256) void prep_k(
    const float* __restrict__ x, short* __restrict__ xb,
    const float* __restrict__ Wqkv, short* __restrict__ WqkvT,
    const float* __restrict__ Wout, short* __restrict__ WoutT,
    float* __restrict__ cost, float* __restrict__ sint) {
  __shared__ float t[64][65];
  const int bx = blockIdx.x, tid = threadIdx.x;
  if (bx < 1024) {
    int base = bx * 4096 + tid * 4;
#pragma unroll
    for (int rep = 0; rep < 4; ++rep) {
      int i = base + rep * 1024;
      float4 v = *(const float4*)(x + i);
      *(short4*)(xb + i) = make_short4(tobf(v.x), tobf(v.y), tobf(v.z), tobf(v.w));
    }
  } else if (bx < 1664) {
    const float* in;
    short* out;
    int C, bb;
    if (bx < 1408) { in = Wqkv; out = WqkvT; C = 1536; bb = bx - 1024; }
    else           { in = Wout; out = WoutT; C = 1024; bb = bx - 1408; }
    const int R = 1024;
    int nc = C >> 6;
    int br = bb / nc, bc = bb % nc;
    int lr = tid >> 6, lc = tid & 63;
#pragma unroll
    for (int j = 0; j < 16; ++j) {
      int r = j * 4 + lr;
      t[r][lc] = in[(size_t)(br * 64 + r) * C + bc * 64 + lc];
    }
    __syncthreads();
#pragma unroll
    for (int j = 0; j < 16; ++j) {
      int r = j * 4 + lr;
      out[(size_t)(bc * 64 + r) * R + br * 64 + lc] = tobf(t[lc][r]);
    }
  } else {
    int t2 = (bx - 1664) * 256 + tid;  // < 65536
    int s = t2 >> 5, f = t2 & 31;
    float inv = __expf(-(float)f * (logf(50000.0f) / 32.0f));
    float a = (float)s * inv;
    cost[t2] = cosf(a);
    sint[t2] = sinf(a);
  }
}

// ---------- GEMM: C[M][N] = A[M][K](bf16) * Bt[N][K](bf16)^T + bias ----------
// MODE 0: QKV projection, RoPE + q-prescale fused in epilogue, bf16 out
// MODE 1: out projection, f32 out
template <int MODE>
__global__ __launch_bounds__(256) void gemm128_k(
    const short* __restrict__ A, const short* __restrict__ Bt,
    const float* __restrict__ bias, void* __restrict__ Cout,
    int M, int N, int K,
    const float* __restrict__ cost, const float* __restrict__ sint) {
  __shared__ short As[128 * 64];
  __shared__ short Bs[128 * 64];
  const int ntile = N >> 7;
  const int bm = blockIdx.x / ntile, bn = blockIdx.x % ntile;
  const int tid = threadIdx.x, w = tid >> 6, l = tid & 63;
  const int c = l & 15, g = l >> 4;
  const int wm = w >> 1, wn = w & 1;
  const int m0 = bm * 128, n0 = bn * 128;

  f32x4 acc[4][4] = {};

  for (int k0 = 0; k0 < K; k0 += 64) {
#pragma unroll
    for (int j = 0; j < 4; ++j) {
      int rb = j * 32 + w * 8;
      int row = rb + (l >> 3);
      int colel = ((l & 7) ^ swz(row)) * 8;  // pre-swizzled source (rule #21)
      GLDS16(A + (size_t)(m0 + row) * K + k0 + colel, &As[rb * 64]);
      GLDS16(Bt + (size_t)(n0 + row) * K + k0 + colel, &Bs[rb * 64]);
    }
    __syncthreads();
#pragma unroll
    for (int kk = 0; kk < 2; ++kk) {
      short8 af[4], bf[4];
#pragma unroll
      for (int mi = 0; mi < 4; ++mi) {
        int row = wm * 64 + mi * 16 + c;
        af[mi] = *(const short8*)&As[row * 64 + ((kk * 4 + g) ^ swz(row)) * 8];
      }
#pragma unroll
      for (int ni = 0; ni < 4; ++ni) {
        int row = wn * 64 + ni * 16 + c;
        bf[ni] = *(const short8*)&Bs[row * 64 + ((kk * 4 + g) ^ swz(row)) * 8];
      }
#pragma unroll
      for (int mi = 0; mi < 4; ++mi)
#pragma unroll
        for (int ni = 0; ni < 4; ++ni)
          acc[mi][ni] = __builtin_amdgcn_mfma_f32_16x16x32_bf16(af[mi], bf[ni], acc[mi][ni], 0, 0, 0);
    }
    __syncthreads();
  }

#pragma unroll
  for (int mi = 0; mi < 4; ++mi)
#pragma unroll
    for (int r = 0; r < 4; ++r) {
      int m = m0 + wm * 64 + mi * 16 + g * 4 + r;
      int s = m & 2047;
#pragma unroll
      for (int ni = 0; ni < 4; ++ni) {
        int n = n0 + wn * 64 + ni * 16 + c;
        float v = acc[mi][ni][r] + bias[n];
        if (MODE == 0) {
          if (n < 1280) {  // q or k region: apply RoPE
            int d = n & 63, f = d & 31;
            float cs = cost[s * 32 + f], sn = sint[s * 32 + f];
            float partner = acc[mi][ni ^ 2][r] + bias[n ^ 32];
            v = (d < 32) ? (v * cs - partner * sn) : (v * cs + partner * sn);
          }
          if (n < 1024) v *= QSCALE;  // q prescale (commutes with rotation)
          ((short*)Cout)[(size_t)m * N + n] = tobf(v);
        } else {
          ((float*)Cout)[(size_t)m * N + n] = v;
        }
      }
    }
}

// ---------- flash attention (causal, GQA) ----------
// Swapped QK^T (S^T = mfma(K,Q)) -> per-lane in-register softmax in log2
// domain (q pre-scaled by 0.125*log2e), defer-max (T13), paired causal
// subtiles for uniform work, double-buffered K/V prefetch, hoisted K/V
// fragment reads shared by both subtiles, setprio around MFMA (T5).
// qkv: [4096][1536] bf16 (q 0..1023, k 1024..1279, v 1280..1535), RoPE applied
// aout: [4096][1024] bf16
__global__ __launch_bounds__(256) void attn_k(const short* __restrict__ qkv,
                                              short* __restrict__ aout) {
  __shared__ short Ks[2][64 * 64];
  __shared__ short Vt[2][64 * 64];
  __shared__ short Ps[4][16 * 64];  // per-wave 16x64 P tile

  const int bx = blockIdx.x;
  const int pr = bx & 15;
  const int h = (bx >> 4) & 15;
  const int b = bx >> 8;
  const int hg = h >> 2;
  const int tid = threadIdx.x, w = tid >> 6, l = tid & 63;
  const int c = l & 15, g = l >> 4;
  const int qa = pr, qb = 31 - pr;
  const size_t rowbase = (size_t)(b * 2048) * 1536;

  // ---- stage Qa -> Ks[0], Qb -> Ks[1]; read Q fragments ----
#pragma unroll
  for (int j = 0; j < 2; ++j) {
    int rb = w * 16 + j * 8;
    int row = rb + (l >> 3);
    int colel = ((l & 7) ^ swz(row)) * 8;
    GLDS16(qkv + rowbase + (size_t)(qa * 64 + row) * 1536 + h * 64 + colel, &Ks[0][rb * 64]);
    GLDS16(qkv + rowbase + (size_t)(qb * 64 + row) * 1536 + h * 64 + colel, &Ks[1][rb * 64]);
  }
  __syncthreads();
  short8 aqa[2], aqb[2];
#pragma unroll
  for (int kk = 0; kk < 2; ++kk) {
    int row = w * 16 + c;
    aqa[kk] = *(const short8*)&Ks[0][row * 64 + ((kk * 4 + g) ^ swz(row)) * 8];
    aqb[kk] = *(const short8*)&Ks[1][row * 64 + ((kk * 4 + g) ^ swz(row)) * 8];
  }
  __syncthreads();

  // ---- prologue: stage K(0) -> Ks[0], V(0) -> regs -> Vt[0] ----
  {
#pragma unroll
    for (int i = 0; i < 2; ++i) {
      int rb = w * 16 + i * 8;
      int row = rb + (l >> 3);
      int colel = ((l & 7) ^ swz(row)) * 8;
      GLDS16(qkv + rowbase + (size_t)row * 1536 + 1024 + hg * 64 + colel, &Ks[0][rb * 64]);
    }
    const int kp0 = tid >> 3, kp1 = 32 + (tid >> 3), d0 = (tid & 7) * 8;
    int4 va = *(const int4*)(qkv + rowbase + (size_t)kp0 * 1536 + 1280 + hg * 64 + d0);
    int4 vb = *(const int4*)(qkv + rowbase + (size_t)kp1 * 1536 + 1280 + hg * 64 + d0);
    short sv[8];
    *(int4*)sv = va;
#pragma unroll
    for (int jj = 0; jj < 8; ++jj) {
      int row = d0 + jj;
      Vt[0][row * 64 + (((kp0 >> 3) ^ swz(row)) * 8) + (kp0 & 7)] = sv[jj];
    }
    *(int4*)sv = vb;
#pragma unroll
    for (int jj = 0; jj < 8; ++jj) {
      int row = d0 + jj;
      Vt[0][row * 64 + (((kp1 >> 3) ^ swz(row)) * 8) + (kp1 & 7)] = sv[jj];
    }
  }
  __syncthreads();

  f32x4 acco[2][4] = {};
  float mrun[2] = {-1e30f, -1e30f};
  float lrun[2] = {0.f, 0.f};
  short* Pw = &Ps[w][0];

  for (int j = 0; j <= qb; ++j) {
    const int cur = j & 1, nxt = cur ^ 1;
    const bool pf = (j < qb);
    int4 pva, pvb;
    const int kp0 = tid >> 3, kp1 = 32 + (tid >> 3), d0 = (tid & 7) * 8;

    if (pf) {  // issue next-tile loads BEFORE compute (latency hides under MFMA/softmax)
#pragma unroll
      for (int i = 0; i < 2; ++i) {
        int rb = w * 16 + i * 8;
        int row = rb + (l >> 3);
        int colel = ((l & 7) ^ swz(row)) * 8;
        GLDS16(qkv + rowbase + (size_t)((j + 1) * 64 + row) * 1536 + 1024 + hg * 64 + colel,
               &Ks[nxt][rb * 64]);
      }
      pva = *(const int4*)(qkv + rowbase + (size_t)((j + 1) * 64 + kp0) * 1536 + 1280 + hg * 64 + d0);
      pvb = *(const int4*)(qkv + rowbase + (size_t)((j + 1) * 64 + kp1) * 1536 + 1280 + hg * 64 + d0);
    }

    // hoisted K/V fragment reads (shared by both subtiles)
    short8 bk[2][4], bv[2][4];
#pragma unroll
    for (int kk = 0; kk < 2; ++kk)
#pragma unroll
      for (int nb = 0; nb < 4; ++nb) {
        int row = nb * 16 + c;
        int cs = ((kk * 4 + g) ^ swz(row)) * 8;
        bk[kk][nb] = *(const short8*)&Ks[cur][row * 64 + cs];
        bv[kk][nb] = *(const short8*)&Vt[cur][row * 64 + cs];
      }

#pragma unroll
    for (int sub = 1; sub >= 0; --sub) {
      if (sub == 0 && j > qa) continue;  // block-uniform branch
      const int qs = sub ? qb : qa;
      const bool diag = (j == qs);

      // S^T = K * Q^T : lane (c,g) holds S[q=c][k=nb*16+g*4+r] (log2 domain)
      f32x4 sfr[4] = {};
      __builtin_amdgcn_s_setprio(1);
#pragma unroll
      for (int kk = 0; kk < 2; ++kk)
#pragma unroll
        for (int nb = 0; nb < 4; ++nb)
          sfr[nb] = __builtin_amdgcn_mfma_f32_16x16x32_bf16(
              bk[kk][nb], sub ? aqb[kk] : aqa[kk], sfr[nb], 0, 0, 0);
      __builtin_amdgcn_s_setprio(0);

      // causal mask (diag tile only; scale already folded into q)
      if (diag) {
#pragma unroll
        for (int nb = 0; nb < 4; ++nb)
#pragma unroll
          for (int r = 0; r < 4; ++r)
            if (nb * 16 + g * 4 + r > w * 16 + c) sfr[nb][r] = -1e30f;
      }

      // in-register online softmax, log2 domain, defer-max (T13)
      float mx = fmaxf(fmaxf(sfr[0][0], sfr[0][1]), fmaxf(sfr[0][2], sfr[0][3]));
#pragma unroll
      for (int nb = 1; nb < 4; ++nb)
        mx = fmaxf(mx, fmaxf(fmaxf(sfr[nb][0], sfr[nb][1]), fmaxf(sfr[nb][2], sfr[nb][3])));
      mx = fmaxf(mx, __shfl_xor(mx, 16, 64));
      mx = fmaxf(mx, __shfl_xor(mx, 32, 64));
      if (!__all(mx <= mrun[sub] + 8.0f)) {  // rare rescale path
        float mnew = fmaxf(mrun[sub], mx);
        float sc = exp2f(mrun[sub] - mnew);
        mrun[sub] = mnew;
        lrun[sub] *= sc;
        float scb[4];
#pragma unroll
        for (int r = 0; r < 4; ++r) scb[r] = __shfl(sc, g * 4 + r, 64);
#pragma unroll
        for (int nb = 0; nb < 4; ++nb)
#pragma unroll
          for (int r = 0; r < 4; ++r) acco[sub][nb][r] *= scb[r];
      }
      float rs = 0.f;
#pragma unroll
      for (int nb = 0; nb < 4; ++nb)
#pragma unroll
        for (int r = 0; r < 4; ++r) {
          float p = exp2f(sfr[nb][r] - mrun[sub]);
          sfr[nb][r] = p;
          rs += p;
        }
      rs += __shfl_xor(rs, 16, 64);
      rs += __shfl_xor(rs, 32, 64);
      lrun[sub] += rs;

      // P -> wave-private LDS (packed 4x bf16 = consecutive k), 16B-granular swizzle
#pragma unroll
      for (int nb = 0; nb < 4; ++nb) {
        short4 pv;
        pv.x = tobf(sfr[nb][0]);
        pv.y = tobf(sfr[nb][1]);
        pv.z = tobf(sfr[nb][2]);
        pv.w = tobf(sfr[nb][3]);
        int pslot = (nb * 2 + (g >> 1)) ^ swz(c);
        *(short4*)&Pw[c * 64 + pslot * 8 + (g & 1) * 4] = pv;
      }

      // PV: O[q][d] += P * V
      __builtin_amdgcn_s_setprio(1);
#pragma unroll
      for (int kk = 0; kk < 2; ++kk) {
        short8 ap = *(const short8*)&Pw[c * 64 + (((kk * 4 + g) ^ swz(c)) * 8)];
#pragma unroll
        for (int nb = 0; nb < 4; ++nb)
          acco[sub][nb] = __builtin_amdgcn_mfma_f32_16x16x32_bf16(ap, bv[kk][nb], acco[sub][nb], 0, 0, 0);
      }
      __builtin_amdgcn_s_setprio(0);
    }

    if (pf) {  // land prefetched V into next buffer (compiler waits vmcnt for pva/pvb)
      short sv[8];
      *(int4*)sv = pva;
#pragma unroll
      for (int jj = 0; jj < 8; ++jj) {
        int row = d0 + jj;
        Vt[nxt][row * 64 + (((kp0 >> 3) ^ swz(row)) * 8) + (kp0 & 7)] = sv[jj];
      }
      *(int4*)sv = pvb;
#pragma unroll
      for (int jj = 0; jj < 8; ++jj) {
        int row = d0 + jj;
        Vt[nxt][row * 64 + (((kp1 >> 3) ^ swz(row)) * 8) + (kp1 & 7)] = sv[jj];
      }
    }
    __syncthreads();
  }

  // epilogue: broadcast 1/l to acco layout, store bf16
#pragma unroll
  for (int sub = 0; sub < 2; ++sub) {
    const int qs = sub ? qb : qa;
    float li = 1.0f / lrun[sub];
    float lb[4];
#pragma unroll
    for (int r = 0; r < 4; ++r) lb[r] = __shfl(li, g * 4 + r, 64);
#pragma unroll
    for (int nb = 0; nb < 4; ++nb)
#pragma unroll
      for (int r = 0; r < 4; ++r) {
        int m = b * 2048 + qs * 64 + w * 16 + g * 4 + r;
        int n = h * 64 + nb * 16 + c;
        aout[(size_t)m * 1024 + n] = tobf(acco[sub][nb][r] * lb[r]);
      }
  }
}

// ---------- launch ----------
extern "C" void kernel_launch(void* const* d_in, const int* in_sizes, int n_in,
                              void* d_out, int out_size, void* d_ws, size_t ws_size,
                              hipStream_t stream) {
  const float* x    = (const float*)d_in[0];
  const float* Wqkv = (const float*)d_in[1];
  const float* bqkv = (const float*)d_in[2];
  const float* Wout = (const float*)d_in[3];
  const float* bout = (const float*)d_in[4];

  char* ws = (char*)d_ws;
  short* xb    = (short*)ws; ws += 8388608;    // x bf16 [4096][1024]
  short* WqkvT = (short*)ws; ws += 3145728;    // [1536][1024] bf16
  short* WoutT = (short*)ws; ws += 2097152;    // [1024][1024] bf16
  short* qkvb  = (short*)ws; ws += 12582912;   // [4096][1536] bf16 (post-RoPE)
  short* attnb = (short*)ws; ws += 8388608;    // [4096][1024] bf16
  float* cost  = (float*)ws; ws += 262144;     // [2048][32]
  float* sint  = (float*)ws; ws += 262144;

  prep_k<<<1920, 256, 0, stream>>>(x, xb, Wqkv, WqkvT, Wout, WoutT, cost, sint);
  gemm128_k<0><<<384, 256, 0, stream>>>(xb, WqkvT, bqkv, (void*)qkvb, 4096, 1536, 1024, cost, sint);
  attn_k<<<512, 256, 0, stream>>>(qkvb, attnb);
  gemm128_k<1><<<256, 256, 0, stream>>>(attnb, WoutT, bout, d_out, 4096, 1024, 1024, cost, sint);
}

// Round 6
// 130.398 us; speedup vs baseline: 1.0126x; 1.0126x over previous
//
#include <hip/hip_runtime.h>
#include <hip/hip_bf16.h>

// ---------- types ----------
typedef __attribute__((ext_vector_type(8))) short short8;
typedef __attribute__((ext_vector_type(4))) float f32x4;

__device__ __forceinline__ short tobf(float f) {
  __hip_bfloat16 h = __float2bfloat16(f);
  return *reinterpret_cast<short*>(&h);
}

// XOR swizzle of the 16B-column index within a 128B LDS row (G4 / T2).
__device__ __forceinline__ int swz(int row) { return (row ^ (row >> 3)) & 7; }

#define GLDS16(gp, lp) __builtin_amdgcn_global_load_lds( \
    (__attribute__((address_space(1))) void*)(gp),       \
    (__attribute__((address_space(3))) void*)(lp), 16, 0, 0)

// q pre-scale folded into QKV-GEMM epilogue: S = (q*alpha)·k is then in
// log2 domain with the 1/sqrt(64) attention scale included -> attn uses exp2.
#define QSCALE 0.18033688011112042f  // 0.125 * log2(e)

// ---------- fused prep kernel ----------
// blocks 0..1023    : x f32 -> bf16 (4096x1024)
// blocks 1024..1407 : transpose Wqkv [1024][1536] -> [1536][1024] bf16
// blocks 1408..1663 : transpose Wout [1024][1024] -> [1024][1024] bf16
// blocks 1664..1919 : RoPE tables [2048][32] cos/sin
__global__ __launch_bounds__(256) void prep_k(
    const float* __restrict__ x, short* __restrict__ xb,
    const float* __restrict__ Wqkv, short* __restrict__ WqkvT,
    const float* __restrict__ Wout, short* __restrict__ WoutT,
    float* __restrict__ cost, float* __restrict__ sint) {
  __shared__ float t[64][65];
  const int bx = blockIdx.x, tid = threadIdx.x;
  if (bx < 1024) {
    int base = bx * 4096 + tid * 4;
#pragma unroll
    for (int rep = 0; rep < 4; ++rep) {
      int i = base + rep * 1024;
      float4 v = *(const float4*)(x + i);
      *(short4*)(xb + i) = make_short4(tobf(v.x), tobf(v.y), tobf(v.z), tobf(v.w));
    }
  } else if (bx < 1664) {
    const float* in;
    short* out;
    int C, bb;
    if (bx < 1408) { in = Wqkv; out = WqkvT; C = 1536; bb = bx - 1024; }
    else           { in = Wout; out = WoutT; C = 1024; bb = bx - 1408; }
    const int R = 1024;
    int nc = C >> 6;
    int br = bb / nc, bc = bb % nc;
    int lr = tid >> 6, lc = tid & 63;
#pragma unroll
    for (int j = 0; j < 16; ++j) {
      int r = j * 4 + lr;
      t[r][lc] = in[(size_t)(br * 64 + r) * C + bc * 64 + lc];
    }
    __syncthreads();
#pragma unroll
    for (int j = 0; j < 16; ++j) {
      int r = j * 4 + lr;
      out[(size_t)(bc * 64 + r) * R + br * 64 + lc] = tobf(t[lc][r]);
    }
  } else {
    int t2 = (bx - 1664) * 256 + tid;  // < 65536
    int s = t2 >> 5, f = t2 & 31;
    float inv = __expf(-(float)f * (logf(50000.0f) / 32.0f));
    float a = (float)s * inv;
    cost[t2] = cosf(a);
    sint[t2] = sinf(a);
  }
}

// ---------- GEMM: C[M][N] = A[M][K](bf16) * Bt[N][K](bf16)^T + bias ----------
// MODE 0: QKV projection, RoPE + q-prescale fused in epilogue, bf16 out
// MODE 1: out projection, f32 out
template <int MODE>
__global__ __launch_bounds__(256) void gemm128_k(
    const short* __restrict__ A, const short* __restrict__ Bt,
    const float* __restrict__ bias, void* __restrict__ Cout,
    int M, int N, int K,
    const float* __restrict__ cost, const float* __restrict__ sint) {
  __shared__ short As[128 * 64];
  __shared__ short Bs[128 * 64];
  const int ntile = N >> 7;
  const int bm = blockIdx.x / ntile, bn = blockIdx.x % ntile;
  const int tid = threadIdx.x, w = tid >> 6, l = tid & 63;
  const int c = l & 15, g = l >> 4;
  const int wm = w >> 1, wn = w & 1;
  const int m0 = bm * 128, n0 = bn * 128;

  f32x4 acc[4][4] = {};

  for (int k0 = 0; k0 < K; k0 += 64) {
#pragma unroll
    for (int j = 0; j < 4; ++j) {
      int rb = j * 32 + w * 8;
      int row = rb + (l >> 3);
      int colel = ((l & 7) ^ swz(row)) * 8;  // pre-swizzled source (rule #21)
      GLDS16(A + (size_t)(m0 + row) * K + k0 + colel, &As[rb * 64]);
      GLDS16(Bt + (size_t)(n0 + row) * K + k0 + colel, &Bs[rb * 64]);
    }
    __syncthreads();
#pragma unroll
    for (int kk = 0; kk < 2; ++kk) {
      short8 af[4], bf[4];
#pragma unroll
      for (int mi = 0; mi < 4; ++mi) {
        int row = wm * 64 + mi * 16 + c;
        af[mi] = *(const short8*)&As[row * 64 + ((kk * 4 + g) ^ swz(row)) * 8];
      }
#pragma unroll
      for (int ni = 0; ni < 4; ++ni) {
        int row = wn * 64 + ni * 16 + c;
        bf[ni] = *(const short8*)&Bs[row * 64 + ((kk * 4 + g) ^ swz(row)) * 8];
      }
#pragma unroll
      for (int mi = 0; mi < 4; ++mi)
#pragma unroll
        for (int ni = 0; ni < 4; ++ni)
          acc[mi][ni] = __builtin_amdgcn_mfma_f32_16x16x32_bf16(af[mi], bf[ni], acc[mi][ni], 0, 0, 0);
    }
    __syncthreads();
  }

#pragma unroll
  for (int mi = 0; mi < 4; ++mi)
#pragma unroll
    for (int r = 0; r < 4; ++r) {
      int m = m0 + wm * 64 + mi * 16 + g * 4 + r;
      int s = m & 2047;
#pragma unroll
      for (int ni = 0; ni < 4; ++ni) {
        int n = n0 + wn * 64 + ni * 16 + c;
        float v = acc[mi][ni][r] + bias[n];
        if (MODE == 0) {
          if (n < 1280) {  // q or k region: apply RoPE
            int d = n & 63, f = d & 31;
            float cs = cost[s * 32 + f], sn = sint[s * 32 + f];
            float partner = acc[mi][ni ^ 2][r] + bias[n ^ 32];
            v = (d < 32) ? (v * cs - partner * sn) : (v * cs + partner * sn);
          }
          if (n < 1024) v *= QSCALE;  // q prescale (commutes with rotation)
          ((short*)Cout)[(size_t)m * N + n] = tobf(v);
        } else {
          ((float*)Cout)[(size_t)m * N + n] = v;
        }
      }
    }
}

// ---------- V transpose: qkv v-region -> vT[b*4+hg][64 d][2048 s] ----------
__global__ __launch_bounds__(256) void vtrans_k(const short* __restrict__ qkvb,
                                                short* __restrict__ vT) {
  __shared__ short t[64][68];
  const int bx = blockIdx.x;            // bg*32 + st
  const int st = bx & 31, bg = bx >> 5; // bg = b*4+hg
  const int b = bg >> 2, hg = bg & 3;
  const int tid = threadIdx.x, lr = tid >> 6, lc = tid & 63;
  const size_t inbase = (size_t)(b * 2048 + st * 64) * 1536 + 1280 + hg * 64;
#pragma unroll
  for (int jj = 0; jj < 16; ++jj) {
    int r = jj * 4 + lr;
    t[r][lc] = qkvb[inbase + (size_t)r * 1536 + lc];
  }
  __syncthreads();
  const size_t outbase = (size_t)(bg * 64) * 2048 + st * 64;
#pragma unroll
  for (int jj = 0; jj < 16; ++jj) {
    int d = jj * 4 + lr;
    vT[outbase + (size_t)d * 2048 + lc] = t[lc][d];
  }
}

// ---------- flash attention (causal, GQA) ----------
// One 64-row q-subtile per block (grid 1024 = 4 blocks/CU for occupancy),
// longest-first dispatch. Swapped QK^T -> per-lane in-register log2-domain
// softmax with defer-max; K and pre-transposed V both staged by
// global_load_lds, double-buffered, prefetch issued before compute.
// qkv: [4096][1536] bf16 (q 0..1023 prescaled, k 1024..1279), RoPE applied
// vT:  [8][64][2048] bf16 (per b*4+hg, transposed V)
// aout: [4096][1024] bf16
__global__ __launch_bounds__(256) void attn_k(const short* __restrict__ qkv,
                                              const short* __restrict__ vT,
                                              short* __restrict__ aout) {
  __shared__ short Ks[2][64 * 64];
  __shared__ short Vt[2][64 * 64];
  __shared__ short Ps[4][16 * 64];  // per-wave 16x64 P tile

  const int bx = blockIdx.x;
  const int qt = 31 - (bx >> 5);     // longest blocks dispatch first
  const int bh = bx & 31;
  const int b = bh >> 4, h = bh & 15, hg = h >> 2;
  const int tid = threadIdx.x, w = tid >> 6, l = tid & 63;
  const int c = l & 15, g = l >> 4;
  const size_t rowbase = (size_t)(b * 2048) * 1536;
  const size_t vbase = (size_t)((b * 4 + hg) * 64) * 2048;

  // ---- stage Q tile (rows qt*64..+63) into Ks[0]; read Q fragments ----
#pragma unroll
  for (int j = 0; j < 2; ++j) {
    int rb = w * 16 + j * 8;
    int row = rb + (l >> 3);
    int colel = ((l & 7) ^ swz(row)) * 8;
    GLDS16(qkv + rowbase + (size_t)(qt * 64 + row) * 1536 + h * 64 + colel, &Ks[0][rb * 64]);
  }
  __syncthreads();
  short8 aq[2];
#pragma unroll
  for (int kk = 0; kk < 2; ++kk) {
    int row = w * 16 + c;
    aq[kk] = *(const short8*)&Ks[0][row * 64 + ((kk * 4 + g) ^ swz(row)) * 8];
  }
  __syncthreads();

  // ---- prologue: stage K(0) -> Ks[0], V^T(0) -> Vt[0] ----
#pragma unroll
  for (int i = 0; i < 2; ++i) {
    int rb = w * 16 + i * 8;
    int row = rb + (l >> 3);
    int colel = ((l & 7) ^ swz(row)) * 8;
    GLDS16(qkv + rowbase + (size_t)row * 1536 + 1024 + hg * 64 + colel, &Ks[0][rb * 64]);
    GLDS16(vT + vbase + (size_t)row * 2048 + colel, &Vt[0][rb * 64]);
  }
  __syncthreads();

  f32x4 acco[4] = {};
  float mrun = -1e30f, lrun = 0.f;
  short* Pw = &Ps[w][0];

  for (int j = 0; j <= qt; ++j) {
    const int cur = j & 1, nxt = cur ^ 1;
    const bool pf = (j < qt);

    if (pf) {  // issue next-tile loads BEFORE compute
#pragma unroll
      for (int i = 0; i < 2; ++i) {
        int rb = w * 16 + i * 8;
        int row = rb + (l >> 3);
        int colel = ((l & 7) ^ swz(row)) * 8;
        GLDS16(qkv + rowbase + (size_t)((j + 1) * 64 + row) * 1536 + 1024 + hg * 64 + colel,
               &Ks[nxt][rb * 64]);
        GLDS16(vT + vbase + (size_t)row * 2048 + (j + 1) * 64 + colel, &Vt[nxt][rb * 64]);
      }
    }

    // hoisted K/V fragment reads
    short8 bk[2][4], bv[2][4];
#pragma unroll
    for (int kk = 0; kk < 2; ++kk)
#pragma unroll
      for (int nb = 0; nb < 4; ++nb) {
        int row = nb * 16 + c;
        int cs = ((kk * 4 + g) ^ swz(row)) * 8;
        bk[kk][nb] = *(const short8*)&Ks[cur][row * 64 + cs];
        bv[kk][nb] = *(const short8*)&Vt[cur][row * 64 + cs];
      }

    // S^T = K * Q^T : lane (c,g) holds S[q=c][k=nb*16+g*4+r] (log2 domain)
    f32x4 sfr[4] = {};
    __builtin_amdgcn_s_setprio(1);
#pragma unroll
    for (int kk = 0; kk < 2; ++kk)
#pragma unroll
      for (int nb = 0; nb < 4; ++nb)
        sfr[nb] = __builtin_amdgcn_mfma_f32_16x16x32_bf16(bk[kk][nb], aq[kk], sfr[nb], 0, 0, 0);
    __builtin_amdgcn_s_setprio(0);

    // causal mask (diag tile only; scale already folded into q)
    if (j == qt) {
#pragma unroll
      for (int nb = 0; nb < 4; ++nb)
#pragma unroll
        for (int r = 0; r < 4; ++r)
          if (nb * 16 + g * 4 + r > w * 16 + c) sfr[nb][r] = -1e30f;
    }

    // in-register online softmax, log2 domain, defer-max (T13)
    float mx = fmaxf(fmaxf(sfr[0][0], sfr[0][1]), fmaxf(sfr[0][2], sfr[0][3]));
#pragma unroll
    for (int nb = 1; nb < 4; ++nb)
      mx = fmaxf(mx, fmaxf(fmaxf(sfr[nb][0], sfr[nb][1]), fmaxf(sfr[nb][2], sfr[nb][3])));
    mx = fmaxf(mx, __shfl_xor(mx, 16, 64));
    mx = fmaxf(mx, __shfl_xor(mx, 32, 64));
    if (!__all(mx <= mrun + 8.0f)) {  // rare rescale path
      float mnew = fmaxf(mrun, mx);
      float sc = exp2f(mrun - mnew);
      mrun = mnew;
      lrun *= sc;
      float scb[4];
#pragma unroll
      for (int r = 0; r < 4; ++r) scb[r] = __shfl(sc, g * 4 + r, 64);
#pragma unroll
      for (int nb = 0; nb < 4; ++nb)
#pragma unroll
        for (int r = 0; r < 4; ++r) acco[nb][r] *= scb[r];
    }
    float rs = 0.f;
#pragma unroll
    for (int nb = 0; nb < 4; ++nb)
#pragma unroll
      for (int r = 0; r < 4; ++r) {
        float p = exp2f(sfr[nb][r] - mrun);
        sfr[nb][r] = p;
        rs += p;
      }
    rs += __shfl_xor(rs, 16, 64);
    rs += __shfl_xor(rs, 32, 64);
    lrun += rs;

    // P -> wave-private LDS (packed 4x bf16 = consecutive k), 16B-slot swizzle
#pragma unroll
    for (int nb = 0; nb < 4; ++nb) {
      short4 pv;
      pv.x = tobf(sfr[nb][0]);
      pv.y = tobf(sfr[nb][1]);
      pv.z = tobf(sfr[nb][2]);
      pv.w = tobf(sfr[nb][3]);
      int pslot = (nb * 2 + (g >> 1)) ^ swz(c);
      *(short4*)&Pw[c * 64 + pslot * 8 + (g & 1) * 4] = pv;
    }

    // PV: O[q][d] += P * V
    __builtin_amdgcn_s_setprio(1);
#pragma unroll
    for (int kk = 0; kk < 2; ++kk) {
      short8 ap = *(const short8*)&Pw[c * 64 + (((kk * 4 + g) ^ swz(c)) * 8)];
#pragma unroll
      for (int nb = 0; nb < 4; ++nb)
        acco[nb] = __builtin_amdgcn_mfma_f32_16x16x32_bf16(ap, bv[kk][nb], acco[nb], 0, 0, 0);
    }
    __builtin_amdgcn_s_setprio(0);

    __syncthreads();
  }

  // epilogue: broadcast 1/l to acco layout, store bf16
  float li = 1.0f / lrun;
  float lb[4];
#pragma unroll
  for (int r = 0; r < 4; ++r) lb[r] = __shfl(li, g * 4 + r, 64);
#pragma unroll
  for (int nb = 0; nb < 4; ++nb)
#pragma unroll
    for (int r = 0; r < 4; ++r) {
      int m = b * 2048 + qt * 64 + w * 16 + g * 4 + r;
      int n = h * 64 + nb * 16 + c;
      aout[(size_t)m * 1024 + n] = tobf(acco[nb][r] * lb[r]);
    }
}

// ---------- launch ----------
extern "C" void kernel_launch(void* const* d_in, const int* in_sizes, int n_in,
                              void* d_out, int out_size, void* d_ws, size_t ws_size,
                              hipStream_t stream) {
  const float* x    = (const float*)d_in[0];
  const float* Wqkv = (const float*)d_in[1];
  const float* bqkv = (const float*)d_in[2];
  const float* Wout = (const float*)d_in[3];
  const float* bout = (const float*)d_in[4];

  char* ws = (char*)d_ws;
  short* xb    = (short*)ws; ws += 8388608;    // x bf16 [4096][1024]
  short* WqkvT = (short*)ws; ws += 3145728;    // [1536][1024] bf16
  short* WoutT = (short*)ws; ws += 2097152;    // [1024][1024] bf16
  short* qkvb  = (short*)ws; ws += 12582912;   // [4096][1536] bf16 (post-RoPE)
  short* attnb = (short*)ws; ws += 8388608;    // [4096][1024] bf16
  short* vTb   = (short*)ws; ws += 2097152;    // [8][64][2048] bf16 (V transposed)
  float* cost  = (float*)ws; ws += 262144;     // [2048][32]
  float* sint  = (float*)ws; ws += 262144;

  prep_k<<<1920, 256, 0, stream>>>(x, xb, Wqkv, WqkvT, Wout, WoutT, cost, sint);
  gemm128_k<0><<<384, 256, 0, stream>>>(xb, WqkvT, bqkv, (void*)qkvb, 4096, 1536, 1024, cost, sint);
  vtrans_k<<<256, 256, 0, stream>>>(qkvb, vTb);
  attn_k<<<1024, 256, 0, stream>>>(qkvb, vTb, attnb);
  gemm128_k<1><<<256, 256, 0, stream>>>(attnb, WoutT, bout, d_out, 4096, 1024, 1024, cost, sint);
}